// Round 2
// baseline (289.421 us; speedup 1.0000x reference)
//
#include <hip/hip_runtime.h>
#include <hip/hip_bf16.h>

#define C_ 8
#define B_ 32
#define G_ 2048
#define S_ 32
#define L_ 3

#define NBLK 256
#define NTHR 1024
#define NTOT (NBLK * NTHR)            // 262144 threads, 2 items each
#define TOTAL (C_ * B_ * G_)          // 524288

// ws float offsets
#define OFF_BUF0 0                    // [C][G][B] unnormalized R (for gathers)
#define OFF_MAX  524288               // cmax[4][8], gmax[4]
#define OFF_CNT  524352               // 16 uints (grid barrier counters)
#define OFF_XT   524416               // xT [G][B] = transpose of x
#define ZERO_FLOATS (OFF_XT - OFF_MAX)

__device__ __forceinline__ void atomicMaxPos(float* a, float v) {
    // all values >= 0, so uint compare == float compare
    atomicMax((unsigned*)a, __float_as_uint(v));
}

__device__ __forceinline__ void gridBarrier(unsigned* cnt, int idx) {
    __syncthreads();
    if (threadIdx.x == 0) {
        __threadfence();                         // release: L2 writeback (agent scope)
        atomicAdd(&cnt[idx], 1u);
        while (__hip_atomic_load(&cnt[idx], __ATOMIC_RELAXED,
                                 __HIP_MEMORY_SCOPE_AGENT) < (unsigned)NBLK)
            __builtin_amdgcn_s_sleep(2);
        __threadfence();                         // acquire: invalidate caches
    }
    __syncthreads();
}

__global__ __launch_bounds__(NTHR) void k_fused(const float* __restrict__ x,
                                                const int* __restrict__ I,
                                                float* __restrict__ out,
                                                float* __restrict__ ws) {
    __shared__ int sIdx[64 * 96];       // 64 (c,g) rows x 96 indices
    __shared__ float sT[64 * 33];       // transpose tile (init + out phases)
    __shared__ float sRedA[16], sRedB[16];

    float* buf0 = ws + OFF_BUF0;
    float* cmax = ws + OFF_MAX;         // [4][8]
    float* gmax = ws + OFF_MAX + 32;    // [4]
    unsigned* cnt = (unsigned*)(ws + OFF_CNT);
    float* xT = ws + OFF_XT;

    const int tid = threadIdx.x;
    const int bid = blockIdx.x;
    const int lane = tid & 63;
    const int wv = tid >> 6;

    // ---- stage this block's 64 index rows in LDS (valid all steps) ----
    const int r1 = bid * 32;                       // rows r1..r1+31 (clause cA)
    {
        const int* I1 = I + r1 * (S_ * L_);
        const int* I2 = I + (r1 + 8192) * (S_ * L_);
#pragma unroll
        for (int k = 0; k < 3; ++k) {
            sIdx[tid + 1024 * k] = I1[tid + 1024 * k];
            sIdx[3072 + tid + 1024 * k] = I2[tid + 1024 * k];
        }
    }

    // ---- init: xT[g][b] = x[b][g] (first 64 blocks only) ----
    if (bid < 64) {
        int g0 = bid * 32;
        int bb = tid >> 5, gg = tid & 31;
        sT[gg * 33 + bb] = x[bb * G_ + g0 + gg];   // coalesced read of x rows
        __syncthreads();
        int g = tid >> 5; bb = tid & 31;
        xT[(g0 + g) * B_ + bb] = sT[g * 33 + bb];  // coalesced write
    }
    __syncthreads();                                // sIdx ready for all
    gridBarrier(cnt, 0);

    const int iA = bid * NTHR + tid;
    const int iB = iA + NTOT;
    const int b = tid & 31;
    const int rowloc = tid >> 5;                    // 0..31
    const int cA = r1 >> 11;                        // bid >> 6, in [0,4)
    const int cB = cA + 4;
    const int* idxA = sIdx + rowloc * 96;
    const int* idxB = sIdx + 3072 + rowloc * 96;

    float accA = xT[iA & (TOTAL / C_ - 1)];         // R_0 value (g*32+b)
    float accB = xT[iB & (TOTAL / C_ - 1)];

#pragma unroll 1
    for (int t = 0; t < 4; ++t) {
        const float* Rbase = (t == 0) ? xT : buf0;
        const int cs = (t == 0) ? 0 : (G_ * B_);
        const float gm = (t == 0) ? 0.0f : gmax[t - 1];
        const float sc = (gm > 1.0f) ? (1.0f / gm) : 1.0f;
        const float sc3 = sc * sc * sc;

        // ---- clause phase: r = softor_s(prod_l R[c, I, b]) ----
        const float* RA = Rbase + cA * cs;
        const float* RB = Rbase + cB * cs;

        float lseA, lseB;
        {
            float body[S_];
#pragma unroll
            for (int s = 0; s < S_; ++s) {
                int j0 = idxA[s * 3 + 0], j1 = idxA[s * 3 + 1], j2 = idxA[s * 3 + 2];
                body[s] = RA[(j0 << 5) | b] * RA[(j1 << 5) | b] * RA[(j2 << 5) | b] * sc3;
            }
            float mx = body[0];
#pragma unroll
            for (int s = 1; s < S_; ++s) mx = fmaxf(mx, body[s]);
            float sum = 0.0f;
#pragma unroll
            for (int s = 0; s < S_; ++s) sum += __expf((body[s] - mx) * 100.0f);
            lseA = mx + 0.01f * __logf(sum);
        }
        {
            float body[S_];
#pragma unroll
            for (int s = 0; s < S_; ++s) {
                int j0 = idxB[s * 3 + 0], j1 = idxB[s * 3 + 1], j2 = idxB[s * 3 + 2];
                body[s] = RB[(j0 << 5) | b] * RB[(j1 << 5) | b] * RB[(j2 << 5) | b] * sc3;
            }
            float mx = body[0];
#pragma unroll
            for (int s = 1; s < S_; ++s) mx = fmaxf(mx, body[s]);
            float sum = 0.0f;
#pragma unroll
            for (int s = 0; s < S_; ++s) sum += __expf((body[s] - mx) * 100.0f);
            lseB = mx + 0.01f * __logf(sum);
        }

        // per-clause max (block covers exactly clauses cA, cB)
        float mA = lseA, mB = lseB;
#pragma unroll
        for (int o = 32; o; o >>= 1) {
            mA = fmaxf(mA, __shfl_xor(mA, o, 64));
            mB = fmaxf(mB, __shfl_xor(mB, o, 64));
        }
        if (lane == 0) { sRedA[wv] = mA; sRedB[wv] = mB; }
        __syncthreads();
        if (tid == 0) {
            float a = sRedA[0], bb2 = sRedB[0];
#pragma unroll
            for (int k = 1; k < 16; ++k) { a = fmaxf(a, sRedA[k]); bb2 = fmaxf(bb2, sRedB[k]); }
            atomicMaxPos(&cmax[t * 8 + cA], a);
            atomicMaxPos(&cmax[t * 8 + cB], bb2);
        }
        gridBarrier(cnt, 1 + 2 * t);

        // ---- combine phase: acc = softor2(acc_norm, r_norm), in registers ----
        const float cmA = cmax[t * 8 + cA];
        const float cmB = cmax[t * 8 + cB];
        const float srA = (cmA > 1.0f) ? (1.0f / cmA) : 1.0f;
        const float srB = (cmB > 1.0f) ? (1.0f / cmB) : 1.0f;

        {
            float Rn = accA * sc, rn = lseA * srA;
            float M = fmaxf(Rn, rn), mn = fminf(Rn, rn);
            accA = M + 0.01f * __logf(1.0f + __expf((mn - M) * 100.0f));
            buf0[iA] = accA;
        }
        {
            float Rn = accB * sc, rn = lseB * srB;
            float M = fmaxf(Rn, rn), mn = fminf(Rn, rn);
            accB = M + 0.01f * __logf(1.0f + __expf((mn - M) * 100.0f));
            buf0[iB] = accB;
        }

        // global max of combined values
        float mm = fmaxf(accA, accB);
#pragma unroll
        for (int o = 32; o; o >>= 1) mm = fmaxf(mm, __shfl_xor(mm, o, 64));
        if (lane == 0) sRedA[wv] = mm;
        __syncthreads();
        if (tid == 0) {
            float a = sRedA[0];
#pragma unroll
            for (int k = 1; k < 16; ++k) a = fmaxf(a, sRedA[k]);
            atomicMaxPos(&gmax[t], a);
        }
        gridBarrier(cnt, 2 + 2 * t);
    }

    // ---- out: transpose [C][G][B] -> [C][B][G] with final scale ----
    const float gfin = gmax[3];
    const float scf = (gfin > 1.0f) ? (1.0f / gfin) : 1.0f;
    const int base = bid * 2048;                 // 64 g x 32 b chunk
    const int c = bid >> 5;
    const int g0 = (bid & 31) * 64;
#pragma unroll
    for (int k = 0; k < 2; ++k) {
        int j = tid + k * 1024;
        sT[(j >> 5) * 33 + (j & 31)] = buf0[base + j] * scf;   // coalesced read
    }
    __syncthreads();
#pragma unroll
    for (int k = 0; k < 2; ++k) {
        int j = tid + k * 1024;
        int bb = j >> 6, gg = j & 63;
        out[(c * 32 + bb) * 2048 + g0 + gg] = sT[gg * 33 + bb]; // 256B contiguous/wave
    }
}

extern "C" void kernel_launch(void* const* d_in, const int* in_sizes, int n_in,
                              void* d_out, int out_size, void* d_ws, size_t ws_size,
                              hipStream_t stream) {
    const float* x = (const float*)d_in[0];
    const int* I = (const int*)d_in[1];
    float* out = (float*)d_out;
    float* ws = (float*)d_ws;

    // zero max slots + barrier counters (captured as a memset node)
    hipMemsetAsync(ws + OFF_MAX, 0, ZERO_FLOATS * sizeof(float), stream);

    void* args[] = {(void*)&x, (void*)&I, (void*)&out, (void*)&ws};
    hipLaunchCooperativeKernel((const void*)k_fused, dim3(NBLK), dim3(NTHR),
                               args, 0, stream);
}